// Round 11
// baseline (280.520 us; speedup 1.0000x reference)
//
#include <hip/hip_runtime.h>
#include <math.h>

#define NPTS 1024
#define CAND 224   // 7*32
#define KEFF 64
#define BATCH 2
#define NEGV -1e30f
#define PLANE (BATCH * NPTS * CAND)

// ================================================================ weight prep
__global__ __launch_bounds__(256) void kprep(const float* __restrict__ w0, const float* __restrict__ w1,
                                             const float* __restrict__ w2, const float* __restrict__ w3,
                                             const float* __restrict__ wl, float* __restrict__ wt) {
    __shared__ float tA[32][33];
    __shared__ float tB[32][33];
    int id = blockIdx.x;
    int t = threadIdx.x;
    int row = t >> 5, col = t & 31;
    const float* W = w0; int Cin = 256, Co = 128; float* WtA = wt; float* WtB = wt + 32768;
    int tc = 0, to = 0; bool isWL = false;
    if (id < 32)      { int r = id;      tc = r >> 2; to = r & 3; }
    else if (id < 48) { W = w1; Cin = 128; Co = 128; WtA = wt + 65536;  WtB = wt + 81920;  int r = id - 32; tc = r >> 2; to = r & 3; }
    else if (id < 56) { W = w2; Cin = 128; Co = 64;  WtA = wt + 98304;  WtB = wt + 106496; int r = id - 48; tc = r >> 1; to = r & 1; }
    else if (id < 60) { W = w3; Cin = 64;  Co = 64;  WtA = wt + 114688; WtB = wt + 118784; int r = id - 56; tc = r >> 1; to = r & 1; }
    else { isWL = true; int r = id - 60; tc = r / 12; to = r % 12; }
    if (!isWL) {
#pragma unroll
        for (int r = 0; r < 4; ++r) {
            int o = to * 32 + row + r * 8;
            int c = tc * 32 + col;
            float va = W[(size_t)o * 2 * Cin + c];
            tA[row + r * 8][col] = va;
            tB[row + r * 8][col] = W[(size_t)o * 2 * Cin + Cin + c] - va;
        }
        __syncthreads();
#pragma unroll
        for (int r = 0; r < 4; ++r) {
            int c = tc * 32 + row + r * 8;
            int o = to * 32 + col;
            WtA[(size_t)c * Co + o] = tA[col][row + r * 8];
            WtB[(size_t)c * Co + o] = tB[col][row + r * 8];
        }
    } else {
        float* wlT = wt + 122880;
#pragma unroll
        for (int r = 0; r < 4; ++r) {
            int o = to * 32 + row + r * 8;
            int c = tc * 32 + col;
            tA[row + r * 8][col] = wl[(size_t)o * 384 + c];
        }
        __syncthreads();
#pragma unroll
        for (int r = 0; r < 4; ++r) {
            int c = tc * 32 + row + r * 8;
            int o = to * 32 + col;
            wlT[(size_t)c * 384 + o] = tA[col][row + r * 8];
        }
    }
}

// ================================================================ GEMM (A/Bv/sq) + banded gram partials
struct GP {
    const float* xin; int bstride; int Cin; int Co; int nch; int applyBN;
    const float* WtA; const float* WtB;
    const float* partPrev; const float* gPrev; const float* bePrev;
    float* A; float* Bv; float* sq; float* Dp;
    float* partOut; int partN;
};

__global__ __launch_bounds__(256) void kgemm(GP p) {
    __shared__ float smem[7168];
    __shared__ float shsc[128];
    __shared__ float shsh[128];
    int t = threadIdx.x;
    if (blockIdx.x == 0) {           // zero stats accumulator for this layer (consumed by next launch)
        for (int e = t; e < p.partN; e += 256) p.partOut[e] = 0.f;
    }
    if (p.applyBN && t < p.Cin) {
        const float* pp = p.partPrev;
        float s  = pp[t * 2]     + pp[(p.Cin + t) * 2];
        float s2 = pp[t * 2 + 1] + pp[(p.Cin + t) * 2 + 1];
        const float invc = 1.f / 131072.f;
        float mu = s * invc;
        float var = s2 * invc - mu * mu;
        float rs = rsqrtf(var + 1e-5f);
        float sc = p.gPrev[t] * rs;
        shsc[t] = sc;
        shsh[t] = p.bePrev[t] - mu * sc;
    }
    __syncthreads();
    int nOT = p.Co >> 6;
    int nABx = 32 * nOT * BATCH;
    if ((int)blockIdx.x < nABx) {
        // ---------------- role A: 32n x 64o tile; thread = 4o x 2n
        int id = blockIdx.x;
        int nt = id & 31; int rest = id >> 5;
        int ot = rest % nOT; int b = rest / nOT;
        int tn2 = (t & 15) * 2, to4 = (t >> 4) * 4;
        int n0 = nt * 32, o0 = ot * 64;
        const float* xb = p.xin + (size_t)b * p.bstride + n0;
        float* Xs = smem; float* Wta = smem + 1024; float* Wtb = smem + 3200;
        float2 a2[4], b2[4], s2v;
#pragma unroll
        for (int i = 0; i < 4; ++i) { a2[i] = make_float2(0.f,0.f); b2[i] = make_float2(0.f,0.f); }
        s2v = make_float2(0.f,0.f);
        int xcc0 = t >> 5, xnn = t & 31;
        int wcc0 = t >> 6, woo = t & 63;
        for (int c0 = 0; c0 < p.Cin; c0 += 32) {
            float rx[4], ra[8], rb[8];
#pragma unroll
            for (int k = 0; k < 4; ++k)
                rx[k] = xb[(size_t)(c0 + xcc0 + k * 8) * NPTS + xnn];
#pragma unroll
            for (int k = 0; k < 8; ++k) {
                ra[k] = p.WtA[(size_t)(c0 + wcc0 + k * 4) * p.Co + o0 + woo];
                rb[k] = p.WtB[(size_t)(c0 + wcc0 + k * 4) * p.Co + o0 + woo];
            }
            if (p.applyBN) {
#pragma unroll
                for (int k = 0; k < 4; ++k) {
                    int cc = xcc0 + k * 8;
                    float y = fmaf(rx[k], shsc[c0 + cc], shsh[c0 + cc]);
                    rx[k] = y >= 0.f ? y : 0.2f * y;
                }
            }
            __syncthreads();
#pragma unroll
            for (int k = 0; k < 4; ++k)
                Xs[(xcc0 + k * 8) * 32 + xnn] = rx[k];
#pragma unroll
            for (int k = 0; k < 8; ++k) {
                Wta[(wcc0 + k * 4) * 68 + woo] = ra[k];
                Wtb[(wcc0 + k * 4) * 68 + woo] = rb[k];
            }
            __syncthreads();
#pragma unroll 8
            for (int cc = 0; cc < 32; ++cc) {
                float2 xv = *(const float2*)&Xs[cc * 32 + tn2];
                float4 wa = *(const float4*)&Wta[cc * 68 + to4];
                float4 wb = *(const float4*)&Wtb[cc * 68 + to4];
                s2v.x = fmaf(xv.x, xv.x, s2v.x);
                s2v.y = fmaf(xv.y, xv.y, s2v.y);
                float wav[4] = {wa.x, wa.y, wa.z, wa.w};
                float wbv[4] = {wb.x, wb.y, wb.z, wb.w};
#pragma unroll
                for (int i = 0; i < 4; ++i) {
                    a2[i].x = fmaf(wav[i], xv.x, a2[i].x);
                    a2[i].y = fmaf(wav[i], xv.y, a2[i].y);
                    b2[i].x = fmaf(wbv[i], xv.x, b2[i].x);
                    b2[i].y = fmaf(wbv[i], xv.y, b2[i].y);
                }
            }
        }
        int n = n0 + tn2;
        if (ot == 0 && to4 == 0)
            *(float2*)&p.sq[b * NPTS + n] = s2v;
#pragma unroll
        for (int i = 0; i < 4; ++i) {
            int o = o0 + to4 + i;
            size_t off = ((size_t)(b * p.Co + o)) * NPTS + n;
            *(float2*)&p.A[off] = a2[i];
            *(float2*)&p.Bv[off] = b2[i];
        }
    } else {
        // ---------------- role B: one 32-channel gram partial per block
        int id2 = blockIdx.x - nABx;
        int chunk = id2 % p.nch; int rest = id2 / p.nch;
        int i = rest & 31; int b = rest >> 5;
        int c0 = chunk * 32;
        const float* xb = p.xin + (size_t)b * p.bstride;
        float* Xc = smem;
        int q = t >> 3;
        int wg = t & 7;
        float r[28];
        int rcc[28], rw[28];
#pragma unroll
        for (int k = 0; k < 28; ++k) {
            int e = t + k * 256;
            int cc = e / CAND;
            int w  = e - cc * CAND;
            rcc[k] = cc; rw[k] = w;
            int wb = i - 3 + (w >> 5);
            wb = wb < 0 ? 0 : (wb > 31 ? 31 : wb);
            r[k] = xb[(size_t)(c0 + cc) * NPTS + wb * 32 + (w & 31)];
        }
        if (p.applyBN) {
#pragma unroll
            for (int k = 0; k < 28; ++k) {
                float y = fmaf(r[k], shsc[c0 + rcc[k]], shsh[c0 + rcc[k]]);
                r[k] = y >= 0.f ? y : 0.2f * y;
            }
        }
#pragma unroll
        for (int k = 0; k < 28; ++k)
            Xc[rcc[k] * CAND + rw[k]] = r[k];
        __syncthreads();
        float acc[28];
#pragma unroll
        for (int j = 0; j < 28; ++j) acc[j] = 0.f;
        for (int cc = 0; cc < 32; ++cc) {
            float qv = Xc[cc * CAND + 96 + q];
            const float4* row = (const float4*)&Xc[cc * CAND + wg * 28];
#pragma unroll
            for (int j4 = 0; j4 < 7; ++j4) {
                float4 v = row[j4];
                acc[j4 * 4 + 0] = fmaf(qv, v.x, acc[j4 * 4 + 0]);
                acc[j4 * 4 + 1] = fmaf(qv, v.y, acc[j4 * 4 + 1]);
                acc[j4 * 4 + 2] = fmaf(qv, v.z, acc[j4 * 4 + 2]);
                acc[j4 * 4 + 3] = fmaf(qv, v.w, acc[j4 * 4 + 3]);
            }
        }
        int n = i * 32 + q;
        size_t base = (((size_t)chunk * BATCH + b) * NPTS + n) * CAND + wg * 28;
        float4* outp = (float4*)&p.Dp[base];
#pragma unroll
        for (int j4 = 0; j4 < 7; ++j4)
            outp[j4] = make_float4(acc[j4 * 4], acc[j4 * 4 + 1], acc[j4 * 4 + 2], acc[j4 * 4 + 3]);
    }
}

// ================================================================ fused top-64 select + gather/agg
// block = (ntile of 8 points, b); phase1 = rank-key select (identical math to R9),
// phase2 = per-32-o passes: stage A band, gather, stats via shuffle + atomicAdd.
template<int NCH, int CO, int CHOUT>
__global__ __launch_bounds__(256) void kselagg(const float* __restrict__ Dp,
                                               const float* __restrict__ sq,
                                               const float* __restrict__ A,
                                               const float* __restrict__ Bv,
                                               float* __restrict__ xconM,
                                               float* __restrict__ part) {
    __shared__ __align__(16) float fbuf[7200];     // phase1: keys (8*224 u64 = 14336B); phase2: Atile 32*225
    __shared__ int idxsh[512];                     // 8 n * 64 k (band-relative w)
    unsigned long long* sKeys = (unsigned long long*)fbuf;
    int t = threadIdx.x;
    int v = t >> 6, l = t & 63;
    int b = blockIdx.y;
    int n0 = blockIdx.x * 8;
    int i = n0 >> 5;
    int bandlo = (i - 3) * 32;

    // ---------------- phase 1: build keys for this wave's 2 points
    unsigned long long kj[2][4];
#pragma unroll
    for (int h = 0; h < 2; ++h) {
        int nl = v + h * 4;
        int n = n0 + nl;
        float sqn = sq[b * NPTS + n];
        float pr[4][NCH];
        float sqw[4];
#pragma unroll
        for (int j = 0; j < 4; ++j) {
            int w = l + 64 * j;
            if (w < CAND) {
                size_t off = ((size_t)b * NPTS + n) * CAND + w;
#pragma unroll
                for (int ch = 0; ch < NCH; ++ch)
                    pr[j][ch] = Dp[off + (size_t)ch * PLANE];
                int wb = i - 3 + (w >> 5);
                int wbc = wb < 0 ? 0 : (wb > 31 ? 31 : wb);
                sqw[j] = sq[b * NPTS + wbc * 32 + (w & 31)];
            }
        }
#pragma unroll
        for (int j = 0; j < 4; ++j) {
            int w = l + 64 * j;
            if (w < CAND) {
                float s = 0.f;
#pragma unroll
                for (int ch = 0; ch < NCH; ++ch) s += pr[j][ch];
                int wb = i - 3 + (w >> 5);
                bool valid = (wb >= 0) && (wb < 32);
                float d = 2.f * s - sqn - sqw[j];
                d = valid ? d : NEGV;
                unsigned u = __float_as_uint(d);
                u ^= ((unsigned)((int)u >> 31)) | 0x80000000u;
                unsigned long long key = ((unsigned long long)u << 8) | (unsigned long long)(255 - w);
                kj[h][j] = key;
                sKeys[nl * 224 + w] = key;
            } else {
                kj[h][j] = 0ull;
            }
        }
    }
    __syncthreads();
    // ---------------- rank count (broadcast reads, no conflicts)
#pragma unroll
    for (int h = 0; h < 2; ++h) {
        int nl = v + h * 4;
        int cnt[4] = {0, 0, 0, 0};
        const ulonglong2* row = (const ulonglong2*)(sKeys + nl * 224);
#pragma unroll 2
        for (int w2 = 0; w2 < 112; w2 += 4) {
            ulonglong2 k0 = row[w2], k1 = row[w2 + 1], k2 = row[w2 + 2], k3 = row[w2 + 3];
#pragma unroll
            for (int j = 0; j < 4; ++j) {
                unsigned long long kk = kj[h][j];
                cnt[j] += (int)(k0.x > kk) + (int)(k0.y > kk) + (int)(k1.x > kk) + (int)(k1.y > kk)
                        + (int)(k2.x > kk) + (int)(k2.y > kk) + (int)(k3.x > kk) + (int)(k3.y > kk);
            }
        }
#pragma unroll
        for (int j = 0; j < 4; ++j) {
            int w = l + 64 * j;
            if (w < CAND && cnt[j] < KEFF)
                idxsh[nl * 64 + cnt[j]] = w;    // band-relative
        }
    }
    // ---------------- phase 2: per-32-o passes
    int oL = t >> 3;        // 0..31
    int nl = t & 7;         // 0..7
    int wsub = t & 7;       // staging: w = wsub + m*8
    for (int og = 0; og < CO; og += 32) {
        __syncthreads();    // 1st iter: idxsh/key reads done; later: prev gathers done
#pragma unroll
        for (int m = 0; m < 28; ++m) {
            int w = wsub + m * 8;
            int aidx = bandlo + w;
            aidx = aidx < 0 ? 0 : (aidx > 1023 ? 1023 : aidx);
            fbuf[oL * 225 + w] = A[((size_t)(b * CO + og + oL)) * NPTS + aidx];
        }
        __syncthreads();
        const float* arow = &fbuf[oL * 225];
        const int* ish = &idxsh[nl * 64];
        float s1 = 0.f, s2 = 0.f, mx = -3.4e38f;
#pragma unroll 8
        for (int k = 0; k < KEFF; ++k) {
            float a = arow[ish[k]];
            s1 += a;
            s2 = fmaf(a, a, s2);
            mx = fmaxf(mx, a);
        }
        int n = n0 + nl;
        float bv = Bv[((size_t)(b * CO + og + oL)) * NPTS + n];
        xconM[((size_t)b * 384 + CHOUT + og + oL) * NPTS + n] = mx + bv;
        float c1 = s1 + 64.f * bv;
        float c2 = s2 + 2.f * bv * s1 + 64.f * bv * bv;
#pragma unroll
        for (int m = 1; m < 8; m <<= 1) {
            c1 += __shfl_xor(c1, m);
            c2 += __shfl_xor(c2, m);
        }
        if (nl == 0) {
            atomicAdd(&part[((size_t)(b * CO + og + oL)) * 2 + 0], c1);
            atomicAdd(&part[((size_t)(b * CO + og + oL)) * 2 + 1], c2);
        }
    }
}

// ================================================================ final GEMM with BN+leaky on load
struct FP {
    const float* part0; const float* part1; const float* part2; const float* part3;
    const float* g0; const float* g1; const float* g2; const float* g3;
    const float* be0; const float* be1; const float* be2; const float* be3;
};

__global__ __launch_bounds__(256) void kfinal(const float* __restrict__ xconM,
                                              const float* __restrict__ wlT, FP p,
                                              float* __restrict__ out) {
    __shared__ float Xs[2048];
    __shared__ float Wl[2176];
    __shared__ float shsc[384];
    __shared__ float shsh[384];
    int t = threadIdx.x;
    for (int ch = t; ch < 384; ch += 256) {
        const float* pl; const float* gl; const float* bl; int o, Col;
        if (ch < 128)      { pl = p.part0; gl = p.g0; bl = p.be0; o = ch;       Col = 128; }
        else if (ch < 256) { pl = p.part1; gl = p.g1; bl = p.be1; o = ch - 128; Col = 128; }
        else if (ch < 320) { pl = p.part2; gl = p.g2; bl = p.be2; o = ch - 256; Col = 64;  }
        else               { pl = p.part3; gl = p.g3; bl = p.be3; o = ch - 320; Col = 64;  }
        float s  = pl[o * 2]     + pl[(Col + o) * 2];
        float s2 = pl[o * 2 + 1] + pl[(Col + o) * 2 + 1];
        const float invc = 1.f / 131072.f;
        float mu = s * invc;
        float var = s2 * invc - mu * mu;
        float rs = rsqrtf(var + 1e-5f);
        float sc = gl[o] * rs;
        shsc[ch] = sc;
        shsh[ch] = bl[o] - mu * sc;
    }
    __syncthreads();
    int tn4 = (t & 15) * 4, to4 = (t >> 4) * 4;
    int n0 = blockIdx.x * 64, o0 = blockIdx.y * 64, b = blockIdx.z;
    int cc0 = t >> 6, nn0 = t & 63;
    float4 acc[4];
#pragma unroll
    for (int i = 0; i < 4; ++i) acc[i] = make_float4(0.f,0.f,0.f,0.f);
    for (int c0 = 0; c0 < 384; c0 += 32) {
        float rx[8], rw[8];
#pragma unroll
        for (int k = 0; k < 8; ++k) {
            int cc = cc0 + k * 4;
            rx[k] = xconM[((size_t)b * 384 + c0 + cc) * NPTS + n0 + nn0];
            rw[k] = wlT[(size_t)(c0 + cc) * 384 + o0 + nn0];
        }
#pragma unroll
        for (int k = 0; k < 8; ++k) {
            int cc = cc0 + k * 4;
            float y = fmaf(rx[k], shsc[c0 + cc], shsh[c0 + cc]);
            rx[k] = y >= 0.f ? y : 0.2f * y;
        }
        __syncthreads();
#pragma unroll
        for (int k = 0; k < 8; ++k) {
            int cc = cc0 + k * 4;
            Xs[cc * 64 + nn0] = rx[k];
            Wl[cc * 68 + nn0] = rw[k];
        }
        __syncthreads();
#pragma unroll 4
        for (int cc = 0; cc < 32; ++cc) {
            float4 xv = *(const float4*)&Xs[cc * 64 + tn4];
            float4 wv = *(const float4*)&Wl[cc * 68 + to4];
            float wvv[4] = {wv.x, wv.y, wv.z, wv.w};
#pragma unroll
            for (int i = 0; i < 4; ++i) {
                acc[i].x = fmaf(wvv[i], xv.x, acc[i].x);
                acc[i].y = fmaf(wvv[i], xv.y, acc[i].y);
                acc[i].z = fmaf(wvv[i], xv.z, acc[i].z);
                acc[i].w = fmaf(wvv[i], xv.w, acc[i].w);
            }
        }
    }
#pragma unroll
    for (int i = 0; i < 4; ++i)
        *(float4*)&out[((size_t)b * 384 + o0 + to4 + i) * NPTS + n0 + tn4] = acc[i];
}

extern "C" void kernel_launch(void* const* d_in, const int* in_sizes, int n_in,
                              void* d_out, int out_size, void* d_ws, size_t ws_size,
                              hipStream_t stream) {
    const float* x  = (const float*)d_in[0];
    const float* w[4]  = {(const float*)d_in[1], (const float*)d_in[4], (const float*)d_in[7], (const float*)d_in[10]};
    const float* g[4]  = {(const float*)d_in[2], (const float*)d_in[5], (const float*)d_in[8], (const float*)d_in[11]};
    const float* be[4] = {(const float*)d_in[3], (const float*)d_in[6], (const float*)d_in[9], (const float*)d_in[12]};
    const float* wl = (const float*)d_in[13];

    float* ws    = (float*)d_ws;
    float* xconM = ws;                       // 786432
    float* A     = xconM + 786432;           // 262144
    float* Bv    = A + 262144;               // 262144
    float* sq    = Bv + 262144;              // 2048
    float* Dp    = sq + 2048;                // 8 planes * 458752 = 3670016
    float* part  = Dp + 3670016;             // 2048
    float* wt    = part + 2048;              // 270336

    kprep<<<204, 256, 0, stream>>>(w[0], w[1], w[2], w[3], wl, wt);

    struct LC { const float* xin; int bstride; int Cin; int Co; int nch; int chOut;
                const float* wtA; const float* wtB; };
    LC L[4] = {
        { x,                  256 * 1024, 256, 128, 8, 0,   wt,          wt + 32768  },
        { xconM,              384 * 1024, 128, 128, 4, 128, wt + 65536,  wt + 81920  },
        { xconM + 128 * 1024, 384 * 1024, 128, 64,  4, 256, wt + 98304,  wt + 106496 },
        { xconM + 256 * 1024, 384 * 1024, 64,  64,  2, 320, wt + 114688, wt + 118784 },
    };

    for (int l = 0; l < 4; ++l) {
        GP gp;
        gp.xin = L[l].xin; gp.bstride = L[l].bstride; gp.Cin = L[l].Cin; gp.Co = L[l].Co;
        gp.nch = L[l].nch; gp.applyBN = (l > 0);
        gp.WtA = L[l].wtA; gp.WtB = L[l].wtB;
        gp.partPrev = (l > 0) ? part + (l - 1) * 512 : nullptr;
        gp.gPrev = (l > 0) ? g[l - 1] : nullptr;
        gp.bePrev = (l > 0) ? be[l - 1] : nullptr;
        gp.A = A; gp.Bv = Bv; gp.sq = sq; gp.Dp = Dp;
        gp.partOut = part + l * 512; gp.partN = L[l].Co * BATCH * 2;
        int nAB = 32 * (L[l].Co >> 6) * BATCH;
        int nDist = L[l].nch * 32 * BATCH;
        kgemm<<<nAB + nDist, 256, 0, stream>>>(gp);
        dim3 sg(NPTS / 8, BATCH);
        if (l == 0)      kselagg<8, 128, 0  ><<<sg, 256, 0, stream>>>(Dp, sq, A, Bv, xconM, part + 0);
        else if (l == 1) kselagg<4, 128, 128><<<sg, 256, 0, stream>>>(Dp, sq, A, Bv, xconM, part + 512);
        else if (l == 2) kselagg<4, 64,  256><<<sg, 256, 0, stream>>>(Dp, sq, A, Bv, xconM, part + 1024);
        else             kselagg<2, 64,  320><<<sg, 256, 0, stream>>>(Dp, sq, A, Bv, xconM, part + 1536);
    }

    FP fp;
    fp.part0 = part; fp.part1 = part + 512; fp.part2 = part + 1024; fp.part3 = part + 1536;
    fp.g0 = g[0]; fp.g1 = g[1]; fp.g2 = g[2]; fp.g3 = g[3];
    fp.be0 = be[0]; fp.be1 = be[1]; fp.be2 = be[2]; fp.be3 = be[3];
    kfinal<<<dim3(16, 6, BATCH), 256, 0, stream>>>(xconM, wt + 122880, fp, (float*)d_out);
}